// Round 1
// baseline (351.826 us; speedup 1.0000x reference)
//
#include <hip/hip_runtime.h>

#define BB 64
#define RR 100
#define CC 2048
#define PP 7
#define HH 512

#define S_ELEMS ((size_t)BB * RR * CC)  // 13,107,200

// ws layout (float offsets)
#define WS_F    ((size_t)0)                       // BB*CC*8 = 1,048,576
#define WS_M    (WS_F + (size_t)BB * CC * 8)      // BB*RR*8 = 51,200
#define WS_MBAR (WS_M + (size_t)BB * RR * 8)      // BB*8    = 512
#define WS_SM   (WS_MBAR + (size_t)BB * 8)        // BB*CC   = 131,072

// ---------------- kernel A: F[b,c,k] = sum_j feats[b,c,k,j] ----------------
__global__ __launch_bounds__(256) void kA(const float* __restrict__ feats,
                                          float* __restrict__ F) {
    __shared__ float sbuf[256 * 49];
    const size_t base = (size_t)blockIdx.x * (256 * 49);
    const float4* src = (const float4*)(feats + base);
    float4* dst = (float4*)sbuf;
#pragma unroll
    for (int i = 0; i < 13; ++i) {
        int idx = threadIdx.x + i * 256;
        if (idx < 3136) dst[idx] = src[idx];
    }
    __syncthreads();
    const float* my = sbuf + threadIdx.x * 49;
    float f[7];
#pragma unroll
    for (int k = 0; k < 7; ++k) {
        float s = 0.f;
#pragma unroll
        for (int j = 0; j < 7; ++j) s += my[k * 7 + j];
        f[k] = s;
    }
    size_t bc = (size_t)blockIdx.x * 256 + threadIdx.x;
    float4* o = (float4*)(F + bc * 8);
    o[0] = make_float4(f[0], f[1], f[2], f[3]);
    o[1] = make_float4(f[4], f[5], f[6], 0.f);
}

// ---------------- kernel B: M[b,r,k] = sum_i masks[b,r,i,k]; Mbar = mean_r M
__global__ __launch_bounds__(128) void kB(const float* __restrict__ masks,
                                          float* __restrict__ M,
                                          float* __restrict__ Mbar) {
    __shared__ float sM[128][8];
    int b = blockIdx.x;
    int r = threadIdx.x;
    float m[8] = {0.f, 0.f, 0.f, 0.f, 0.f, 0.f, 0.f, 0.f};
    if (r < RR) {
        const float* p = masks + ((size_t)b * RR + r) * 49;
#pragma unroll
        for (int i = 0; i < 7; ++i)
#pragma unroll
            for (int k = 0; k < 7; ++k) m[k] += p[i * 7 + k];
        float4* Mo = (float4*)(M + ((size_t)b * RR + r) * 8);
        Mo[0] = make_float4(m[0], m[1], m[2], m[3]);
        Mo[1] = make_float4(m[4], m[5], m[6], 0.f);
    }
#pragma unroll
    for (int k = 0; k < 8; ++k) sM[r][k] = m[k];
    __syncthreads();
    if (r < 8) {
        float s = 0.f;
        for (int rr2 = 0; rr2 < RR; ++rr2) s += sM[rr2][r];
        Mbar[b * 8 + r] = s * (1.0f / RR);
    }
}

// ---------------- kernel C: S[b,r,c] = (1/49) dot8(M[b,r], F[b,c]); Sm fused
__global__ __launch_bounds__(256) void kC(const float* __restrict__ Fb,
                                          const float* __restrict__ M,
                                          const float* __restrict__ Mbar,
                                          float* __restrict__ S,
                                          float* __restrict__ Sm) {
    __shared__ float sM[808];
    int b = blockIdx.y;
    const float* Mb = M + (size_t)b * RR * 8;
    for (int i = threadIdx.x; i < 800; i += 256) sM[i] = Mb[i];
    if (threadIdx.x < 8) sM[800 + threadIdx.x] = Mbar[b * 8 + threadIdx.x];
    __syncthreads();
    int c = blockIdx.x * 512 + threadIdx.x * 2;
    const float* Fp = Fb + ((size_t)b * CC + c) * 8;
    float4 a0 = *(const float4*)(Fp);
    float4 a1 = *(const float4*)(Fp + 4);
    float4 e0 = *(const float4*)(Fp + 8);
    float4 e1 = *(const float4*)(Fp + 12);
    float* Sp = S + (size_t)b * RR * CC + c;
    const float inv = 1.0f / 49.0f;
#pragma unroll 4
    for (int r = 0; r < RR; ++r) {
        float4 m0 = *(const float4*)&sM[r * 8];
        float4 m1 = *(const float4*)&sM[r * 8 + 4];
        float va = m0.x * a0.x + m0.y * a0.y + m0.z * a0.z + m0.w * a0.w +
                   m1.x * a1.x + m1.y * a1.y + m1.z * a1.z;
        float vb = m0.x * e0.x + m0.y * e0.y + m0.z * e0.z + m0.w * e0.w +
                   m1.x * e1.x + m1.y * e1.y + m1.z * e1.z;
        *(float2*)&Sp[(size_t)r * CC] = make_float2(va * inv, vb * inv);
    }
    float4 u0 = *(const float4*)&sM[800];
    float4 u1 = *(const float4*)&sM[804];
    float sa = u0.x * a0.x + u0.y * a0.y + u0.z * a0.z + u0.w * a0.w +
               u1.x * a1.x + u1.y * a1.y + u1.z * a1.z;
    float sb = u0.x * e0.x + u0.y * e0.y + u0.z * e0.z + u0.w * e0.w +
               u1.x * e1.x + u1.y * e1.y + u1.z * e1.z;
    *(float2*)&Sm[(size_t)b * CC + c] = make_float2(sa * inv, sb * inv);
}

// ---------------- kernel D: h0/c0 = Sm @ [W1|W2]^T + bias (K-split + atomics)
#define KSPLIT 64
#define KC 32  // CC / KSPLIT
__global__ __launch_bounds__(256) void kD(const float* __restrict__ Sm,
                                          const float* __restrict__ W1,
                                          const float* __restrict__ b1,
                                          const float* __restrict__ W2,
                                          const float* __restrict__ b2,
                                          float* __restrict__ out) {
    __shared__ float sW[KC][260];  // [cc][h], padded: write 4-way ok, read 2-way
    __shared__ float sS[KC][68];   // [cc][b]
    int ht = blockIdx.x;  // 0..3 -> 256-h tile over [W1(512) | W2(512)]
    int ks = blockIdx.y;  // 0..KSPLIT-1
    int c0 = ks * KC;
    const float* W = (ht < 2) ? W1 : W2;
    int hrow0 = (ht & 1) * 256;

    for (int i = threadIdx.x; i < 256 * KC; i += 256) {
        int h = i >> 5, cc = i & 31;
        sW[cc][h] = W[(size_t)(hrow0 + h) * CC + c0 + cc];
    }
    for (int i = threadIdx.x; i < 64 * KC; i += 256) {
        int bb = i >> 5, cc = i & 31;
        sS[cc][bb] = Sm[(size_t)bb * CC + c0 + cc];
    }
    __syncthreads();

    int bg = threadIdx.x & 7;   // 8 groups x 8 b
    int hg = threadIdx.x >> 3;  // 32 groups x 8 h
    float acc[8][8];
#pragma unroll
    for (int i = 0; i < 8; ++i)
#pragma unroll
        for (int j = 0; j < 8; ++j) acc[i][j] = 0.f;

    for (int cc = 0; cc < KC; ++cc) {
        float4 s0 = *(const float4*)&sS[cc][bg * 8];
        float4 s1 = *(const float4*)&sS[cc][bg * 8 + 4];
        float4 w0 = *(const float4*)&sW[cc][hg * 8];
        float4 w1 = *(const float4*)&sW[cc][hg * 8 + 4];
        float fs[8] = {s0.x, s0.y, s0.z, s0.w, s1.x, s1.y, s1.z, s1.w};
        float fw[8] = {w0.x, w0.y, w0.z, w0.w, w1.x, w1.y, w1.z, w1.w};
#pragma unroll
        for (int i = 0; i < 8; ++i)
#pragma unroll
            for (int j = 0; j < 8; ++j) acc[i][j] += fs[i] * fw[j];
    }

    int hglobal = ht * 256 + hg * 8;  // 0..1023 over concat [h0|c0]
    int which = hglobal >> 9;
    int hh = hglobal & 511;
    const float* bias = which ? b2 : b1;
    size_t obase = S_ELEMS + (size_t)which * ((size_t)BB * HH);
#pragma unroll
    for (int i = 0; i < 8; ++i) {
        int bb = bg * 8 + i;
#pragma unroll
        for (int j = 0; j < 8; ++j) {
            float v = acc[i][j];
            if (ks == 0) v += bias[hh + j];
            atomicAdd(&out[obase + (size_t)bb * HH + hh + j], v);
        }
    }
}

extern "C" void kernel_launch(void* const* d_in, const int* in_sizes, int n_in,
                              void* d_out, int out_size, void* d_ws, size_t ws_size,
                              hipStream_t stream) {
    const float* feats = (const float*)d_in[0];
    const float* masks = (const float*)d_in[1];
    const float* W1 = (const float*)d_in[2];
    const float* b1 = (const float*)d_in[3];
    const float* W2 = (const float*)d_in[4];
    const float* b2 = (const float*)d_in[5];
    float* out = (float*)d_out;
    float* ws = (float*)d_ws;
    float* F = ws + WS_F;
    float* M = ws + WS_M;
    float* Mbar = ws + WS_MBAR;
    float* Sm = ws + WS_SM;

    // zero h0/c0 tail (atomic accumulation target)
    hipMemsetAsync(out + S_ELEMS, 0, 2 * (size_t)BB * HH * sizeof(float), stream);

    kA<<<512, 256, 0, stream>>>(feats, F);                 // F row-sums
    kB<<<64, 128, 0, stream>>>(masks, M, Mbar);            // M col-sums + mean
    kC<<<dim3(4, 64), 256, 0, stream>>>(F, M, Mbar, out, Sm);
    kD<<<dim3(4, KSPLIT), 256, 0, stream>>>(Sm, W1, b1, W2, b2, out);
}

// Round 2
// 58.196 us; speedup vs baseline: 6.0456x; 6.0456x over previous
//
#include <hip/hip_runtime.h>

#define BB 64
#define RR 100
#define CC 2048
#define PP 7
#define HH 512

#define S_ELEMS ((size_t)BB * RR * CC)  // 13,107,200

// ws layout (float offsets)
#define WS_F    ((size_t)0)                       // BB*CC*8 = 1,048,576
#define WS_M    (WS_F + (size_t)BB * CC * 8)      // BB*RR*8 = 51,200
#define WS_MBAR (WS_M + (size_t)BB * RR * 8)      // BB*8    = 512
#define WS_SM   (WS_MBAR + (size_t)BB * 8)        // BB*CC   = 131,072
#define WS_PART (WS_SM + (size_t)BB * CC)         // KSPLIT*BB*1024 = 1,048,576

#define KSPLIT 16
#define KCHUNK (CC / KSPLIT)  // 128
#define KC 32

// ---------------- kernel A: F[b,c,k] = sum_j feats[b,c,k,j] ----------------
__global__ __launch_bounds__(256) void kA(const float* __restrict__ feats,
                                          float* __restrict__ F) {
    __shared__ float sbuf[256 * 49];
    const size_t base = (size_t)blockIdx.x * (256 * 49);
    const float4* src = (const float4*)(feats + base);
    float4* dst = (float4*)sbuf;
#pragma unroll
    for (int i = 0; i < 13; ++i) {
        int idx = threadIdx.x + i * 256;
        if (idx < 3136) dst[idx] = src[idx];
    }
    __syncthreads();
    const float* my = sbuf + threadIdx.x * 49;
    float f[7];
#pragma unroll
    for (int k = 0; k < 7; ++k) {
        float s = 0.f;
#pragma unroll
        for (int j = 0; j < 7; ++j) s += my[k * 7 + j];
        f[k] = s;
    }
    size_t bc = (size_t)blockIdx.x * 256 + threadIdx.x;
    float4* o = (float4*)(F + bc * 8);
    o[0] = make_float4(f[0], f[1], f[2], f[3]);
    o[1] = make_float4(f[4], f[5], f[6], 0.f);
}

// ---------------- kernel B: M[b,r,k] = sum_i masks[b,r,i,k]; Mbar = mean_r M
__global__ __launch_bounds__(128) void kB(const float* __restrict__ masks,
                                          float* __restrict__ M,
                                          float* __restrict__ Mbar) {
    __shared__ float sM[128][8];
    int b = blockIdx.x;
    int r = threadIdx.x;
    float m[8] = {0.f, 0.f, 0.f, 0.f, 0.f, 0.f, 0.f, 0.f};
    if (r < RR) {
        const float* p = masks + ((size_t)b * RR + r) * 49;
#pragma unroll
        for (int i = 0; i < 7; ++i)
#pragma unroll
            for (int k = 0; k < 7; ++k) m[k] += p[i * 7 + k];
        float4* Mo = (float4*)(M + ((size_t)b * RR + r) * 8);
        Mo[0] = make_float4(m[0], m[1], m[2], m[3]);
        Mo[1] = make_float4(m[4], m[5], m[6], 0.f);
    }
#pragma unroll
    for (int k = 0; k < 8; ++k) sM[r][k] = m[k];
    __syncthreads();
    if (r < 8) {
        float s = 0.f;
        for (int rr2 = 0; rr2 < RR; ++rr2) s += sM[rr2][r];
        Mbar[b * 8 + r] = s * (1.0f / RR);
    }
}

// ---------------- kernel C: S[b,r,c] = (1/49) dot8(M[b,r], F[b,c]); Sm fused
__global__ __launch_bounds__(256) void kC(const float* __restrict__ Fb,
                                          const float* __restrict__ M,
                                          const float* __restrict__ Mbar,
                                          float* __restrict__ S,
                                          float* __restrict__ Sm) {
    __shared__ float sM[808];
    int b = blockIdx.y;
    const float* Mb = M + (size_t)b * RR * 8;
    for (int i = threadIdx.x; i < 800; i += 256) sM[i] = Mb[i];
    if (threadIdx.x < 8) sM[800 + threadIdx.x] = Mbar[b * 8 + threadIdx.x];
    __syncthreads();
    int c = blockIdx.x * 512 + threadIdx.x * 2;
    const float* Fp = Fb + ((size_t)b * CC + c) * 8;
    float4 a0 = *(const float4*)(Fp);
    float4 a1 = *(const float4*)(Fp + 4);
    float4 e0 = *(const float4*)(Fp + 8);
    float4 e1 = *(const float4*)(Fp + 12);
    float* Sp = S + (size_t)b * RR * CC + c;
    const float inv = 1.0f / 49.0f;
#pragma unroll 4
    for (int r = 0; r < RR; ++r) {
        float4 m0 = *(const float4*)&sM[r * 8];
        float4 m1 = *(const float4*)&sM[r * 8 + 4];
        float va = m0.x * a0.x + m0.y * a0.y + m0.z * a0.z + m0.w * a0.w +
                   m1.x * a1.x + m1.y * a1.y + m1.z * a1.z;
        float vb = m0.x * e0.x + m0.y * e0.y + m0.z * e0.z + m0.w * e0.w +
                   m1.x * e1.x + m1.y * e1.y + m1.z * e1.z;
        *(float2*)&Sp[(size_t)r * CC] = make_float2(va * inv, vb * inv);
    }
    float4 u0 = *(const float4*)&sM[800];
    float4 u1 = *(const float4*)&sM[804];
    float sa = u0.x * a0.x + u0.y * a0.y + u0.z * a0.z + u0.w * a0.w +
               u1.x * a1.x + u1.y * a1.y + u1.z * a1.z;
    float sb = u0.x * e0.x + u0.y * e0.y + u0.z * e0.z + u0.w * e0.w +
               u1.x * e1.x + u1.y * e1.y + u1.z * e1.z;
    *(float2*)&Sm[(size_t)b * CC + c] = make_float2(sa * inv, sb * inv);
}

// ---------------- kernel D1: split-K GEMM partials (no atomics) ------------
// grid (4 h-tiles of 256 over concat [W1;W2], KSPLIT). part[ks][b][hglobal].
__global__ __launch_bounds__(256) void kD1(const float* __restrict__ Sm,
                                           const float* __restrict__ W1,
                                           const float* __restrict__ W2,
                                           float* __restrict__ part) {
    __shared__ float sW[KC][260];
    __shared__ float sS[KC][68];
    int ht = blockIdx.x;  // 0..3
    int ks = blockIdx.y;  // 0..KSPLIT-1
    const float* W = (ht < 2) ? W1 : W2;
    int hrow0 = (ht & 1) * 256;

    float acc[8][8];
#pragma unroll
    for (int i = 0; i < 8; ++i)
#pragma unroll
        for (int j = 0; j < 8; ++j) acc[i][j] = 0.f;

    int bg = threadIdx.x & 7;   // 8 groups x 8 b
    int hg = threadIdx.x >> 3;  // 32 groups x 8 h

    for (int sub = 0; sub < KCHUNK / KC; ++sub) {
        int c0 = ks * KCHUNK + sub * KC;
        for (int i = threadIdx.x; i < 256 * KC; i += 256) {
            int h = i >> 5, cc = i & 31;
            sW[cc][h] = W[(size_t)(hrow0 + h) * CC + c0 + cc];
        }
        for (int i = threadIdx.x; i < 64 * KC; i += 256) {
            int bb = i >> 5, cc = i & 31;
            sS[cc][bb] = Sm[(size_t)bb * CC + c0 + cc];
        }
        __syncthreads();

        for (int cc = 0; cc < KC; ++cc) {
            float4 s0 = *(const float4*)&sS[cc][bg * 8];
            float4 s1 = *(const float4*)&sS[cc][bg * 8 + 4];
            float4 w0 = *(const float4*)&sW[cc][hg * 8];
            float4 w1 = *(const float4*)&sW[cc][hg * 8 + 4];
            float fs[8] = {s0.x, s0.y, s0.z, s0.w, s1.x, s1.y, s1.z, s1.w};
            float fw[8] = {w0.x, w0.y, w0.z, w0.w, w1.x, w1.y, w1.z, w1.w};
#pragma unroll
            for (int i = 0; i < 8; ++i)
#pragma unroll
                for (int j = 0; j < 8; ++j) acc[i][j] += fs[i] * fw[j];
        }
        __syncthreads();
    }

    int hglobal = ht * 256 + hg * 8;  // 0..1023
    float* pp = part + (size_t)ks * (BB * 1024);
#pragma unroll
    for (int i = 0; i < 8; ++i) {
        int bb = bg * 8 + i;
        float* o = pp + (size_t)bb * 1024 + hglobal;
        *(float4*)(o) = make_float4(acc[i][0], acc[i][1], acc[i][2], acc[i][3]);
        *(float4*)(o + 4) = make_float4(acc[i][4], acc[i][5], acc[i][6], acc[i][7]);
    }
}

// ---------------- kernel D2: reduce partials + bias ------------------------
__global__ __launch_bounds__(256) void kD2(const float* __restrict__ part,
                                           const float* __restrict__ b1,
                                           const float* __restrict__ b2,
                                           float* __restrict__ out) {
    int idx = blockIdx.x * 256 + threadIdx.x;  // 0..65535
    int b = idx >> 10;
    int h = idx & 1023;
    float s = (h < HH) ? b1[h] : b2[h - HH];
#pragma unroll
    for (int ks = 0; ks < KSPLIT; ++ks) s += part[(size_t)ks * (BB * 1024) + idx];
    int which = h >> 9;
    out[S_ELEMS + (size_t)which * (BB * HH) + (size_t)b * HH + (h & 511)] = s;
}

extern "C" void kernel_launch(void* const* d_in, const int* in_sizes, int n_in,
                              void* d_out, int out_size, void* d_ws, size_t ws_size,
                              hipStream_t stream) {
    const float* feats = (const float*)d_in[0];
    const float* masks = (const float*)d_in[1];
    const float* W1 = (const float*)d_in[2];
    const float* b1 = (const float*)d_in[3];
    const float* W2 = (const float*)d_in[4];
    const float* b2 = (const float*)d_in[5];
    float* out = (float*)d_out;
    float* ws = (float*)d_ws;
    float* F = ws + WS_F;
    float* M = ws + WS_M;
    float* Mbar = ws + WS_MBAR;
    float* Sm = ws + WS_SM;
    float* part = ws + WS_PART;

    kA<<<512, 256, 0, stream>>>(feats, F);        // F row-sums
    kB<<<64, 128, 0, stream>>>(masks, M, Mbar);   // M col-sums + mean
    kC<<<dim3(4, 64), 256, 0, stream>>>(F, M, Mbar, out, Sm);
    kD1<<<dim3(4, KSPLIT), 256, 0, stream>>>(Sm, W1, W2, part);
    kD2<<<256, 256, 0, stream>>>(part, b1, b2, out);
}

// Round 3
// 36.910 us; speedup vs baseline: 9.5319x; 1.5767x over previous
//
#include <hip/hip_runtime.h>

#define BB 64
#define RR 100
#define CC 2048
#define HH 512

#define S_ELEMS ((size_t)BB * RR * CC)  // 13,107,200

// ws layout (float offsets)
#define WS_F    ((size_t)0)                    // BB*CC*8 = 1,048,576
#define WS_M    (WS_F + (size_t)BB * CC * 8)   // BB*RR*8 = 51,200
#define WS_SM   (WS_M + (size_t)BB * RR * 8)   // BB*CC   = 131,072
#define WS_PART (WS_SM + (size_t)BB * CC)      // KSPLIT*BB*1024 = 2,097,152

#define KSPLIT 32
#define KCHUNK (CC / KSPLIT)  // 64
#define KC 32

// ---- kernel A2: masks[b]->M,Mbar (in-block); feats->F; Sm = Mbar.F/49 -----
// grid (8 c-tiles, 64 b), 256 threads. Each block re-reduces masks[b] (19.6KB,
// L2-hot for 7/8 blocks) to avoid a separate kernel + dependency gap.
__global__ __launch_bounds__(256) void kA2(const float* __restrict__ feats,
                                           const float* __restrict__ masks,
                                           float* __restrict__ F,
                                           float* __restrict__ M,
                                           float* __restrict__ Sm) {
    __shared__ float smem[12544];  // phase1: [256][8] m-rows; phase2: feats tile
    __shared__ float sMbar[8];
    int b = blockIdx.y;
    int ctile = blockIdx.x;
    int t = threadIdx.x;

    // phase 1: per-r column sums of masks[b,r,:,:]
    float m[8] = {0.f, 0.f, 0.f, 0.f, 0.f, 0.f, 0.f, 0.f};
    if (t < RR) {
        const float* p = masks + ((size_t)b * RR + t) * 49;
#pragma unroll
        for (int i = 0; i < 7; ++i)
#pragma unroll
            for (int k = 0; k < 7; ++k) m[k] += p[i * 7 + k];
    }
#pragma unroll
    for (int k = 0; k < 8; ++k) smem[t * 8 + k] = m[k];
    __syncthreads();
    if (t < 8) {
        float s = 0.f;
        for (int r = 0; r < RR; ++r) s += smem[r * 8 + t];
        sMbar[t] = s * (1.0f / RR);
    }
    if (ctile == 0 && t < RR) {  // one writer per b for M
        float4* Mo = (float4*)(M + ((size_t)b * RR + t) * 8);
        Mo[0] = make_float4(m[0], m[1], m[2], m[3]);
        Mo[1] = make_float4(m[4], m[5], m[6], 0.f);
    }
    __syncthreads();  // smem reads done; sMbar visible

    // phase 2: stage feats[b, c0..c0+255, :, :] (50 KB) and row-sum
    const size_t base = ((size_t)b * CC + (size_t)ctile * 256) * 49;
    const float4* src = (const float4*)(feats + base);
    float4* dst = (float4*)smem;
#pragma unroll
    for (int i = 0; i < 13; ++i) {
        int idx = t + i * 256;
        if (idx < 3136) dst[idx] = src[idx];
    }
    __syncthreads();
    const float* my = smem + t * 49;
    float f[7];
#pragma unroll
    for (int k = 0; k < 7; ++k) {
        float s = 0.f;
#pragma unroll
        for (int j = 0; j < 7; ++j) s += my[k * 7 + j];
        f[k] = s;
    }
    int c = ctile * 256 + t;
    float4* o = (float4*)(F + ((size_t)b * CC + c) * 8);
    o[0] = make_float4(f[0], f[1], f[2], f[3]);
    o[1] = make_float4(f[4], f[5], f[6], 0.f);
    float sm = f[0] * sMbar[0] + f[1] * sMbar[1] + f[2] * sMbar[2] +
               f[3] * sMbar[3] + f[4] * sMbar[4] + f[5] * sMbar[5] +
               f[6] * sMbar[6];
    Sm[(size_t)b * CC + c] = sm * (1.0f / 49.0f);
}

// ---- kernel E: blocks [0,128): split-K GEMM partials; [128,384): S writer --
__global__ __launch_bounds__(256) void kE(const float* __restrict__ Fb,
                                          const float* __restrict__ M,
                                          const float* __restrict__ Sm,
                                          const float* __restrict__ W1,
                                          const float* __restrict__ W2,
                                          float* __restrict__ S,
                                          float* __restrict__ part) {
    __shared__ float smem[10496];  // GEMM: sW[32][260] + sS[32][68]; kC: [0..807]
    int t = threadIdx.x;

    if (blockIdx.x < 128) {
        // ---- GEMM partials: acc[b][h] over K-chunk of 64 ----
        int ht = blockIdx.x & 3;   // 0..3 -> 256-h tile over concat [W1;W2]
        int ks = blockIdx.x >> 2;  // 0..31
        const float* W = (ht < 2) ? W1 : W2;
        int hrow0 = (ht & 1) * 256;
        float* sW = smem;          // [cc][260]
        float* sS = smem + 8320;   // [cc][68]

        float acc[8][8];
#pragma unroll
        for (int i = 0; i < 8; ++i)
#pragma unroll
            for (int j = 0; j < 8; ++j) acc[i][j] = 0.f;

        int bg = t & 7;   // 8 groups x 8 b
        int hg = t >> 3;  // 32 groups x 8 h

        for (int sub = 0; sub < KCHUNK / KC; ++sub) {
            int c0 = ks * KCHUNK + sub * KC;
            for (int i = t; i < 256 * KC; i += 256) {
                int h = i >> 5, cc = i & 31;
                sW[cc * 260 + h] = W[(size_t)(hrow0 + h) * CC + c0 + cc];
            }
            for (int i = t; i < 64 * KC; i += 256) {
                int bb = i >> 5, cc = i & 31;
                sS[cc * 68 + bb] = Sm[(size_t)bb * CC + c0 + cc];
            }
            __syncthreads();
            for (int cc = 0; cc < KC; ++cc) {
                float4 s0 = *(const float4*)&sS[cc * 68 + bg * 8];
                float4 s1 = *(const float4*)&sS[cc * 68 + bg * 8 + 4];
                float4 w0 = *(const float4*)&sW[cc * 260 + hg * 8];
                float4 w1 = *(const float4*)&sW[cc * 260 + hg * 8 + 4];
                float fs[8] = {s0.x, s0.y, s0.z, s0.w, s1.x, s1.y, s1.z, s1.w};
                float fw[8] = {w0.x, w0.y, w0.z, w0.w, w1.x, w1.y, w1.z, w1.w};
#pragma unroll
                for (int i = 0; i < 8; ++i)
#pragma unroll
                    for (int j = 0; j < 8; ++j) acc[i][j] += fs[i] * fw[j];
            }
            __syncthreads();
        }

        int hglobal = ht * 256 + hg * 8;  // 0..1023
        float* pp = part + (size_t)ks * (BB * 1024);
#pragma unroll
        for (int i = 0; i < 8; ++i) {
            int bb = bg * 8 + i;
            float* o = pp + (size_t)bb * 1024 + hglobal;
            *(float4*)(o) = make_float4(acc[i][0], acc[i][1], acc[i][2], acc[i][3]);
            *(float4*)(o + 4) = make_float4(acc[i][4], acc[i][5], acc[i][6], acc[i][7]);
        }
    } else {
        // ---- S writer: S[b,r,c] = (1/49) dot8(M[b,r], F[b,c]) ----
        int bid = blockIdx.x - 128;
        int b = bid >> 2;
        int ctile = bid & 3;
        const float* Mb = M + (size_t)b * RR * 8;
        for (int i = t; i < 800; i += 256) smem[i] = Mb[i];
        __syncthreads();
        int c = ctile * 512 + t * 2;
        const float* Fp = Fb + ((size_t)b * CC + c) * 8;
        float4 a0 = *(const float4*)(Fp);
        float4 a1 = *(const float4*)(Fp + 4);
        float4 e0 = *(const float4*)(Fp + 8);
        float4 e1 = *(const float4*)(Fp + 12);
        float* Sp = S + (size_t)b * RR * CC + c;
        const float inv = 1.0f / 49.0f;
#pragma unroll 4
        for (int r = 0; r < RR; ++r) {
            float4 m0 = *(const float4*)&smem[r * 8];
            float4 m1 = *(const float4*)&smem[r * 8 + 4];
            float va = m0.x * a0.x + m0.y * a0.y + m0.z * a0.z + m0.w * a0.w +
                       m1.x * a1.x + m1.y * a1.y + m1.z * a1.z;
            float vb = m0.x * e0.x + m0.y * e0.y + m0.z * e0.z + m0.w * e0.w +
                       m1.x * e1.x + m1.y * e1.y + m1.z * e1.z;
            *(float2*)&Sp[(size_t)r * CC] = make_float2(va * inv, vb * inv);
        }
    }
}

// ---- kernel D2: out = sum_ks part + bias --------------------------------
__global__ __launch_bounds__(256) void kD2(const float* __restrict__ part,
                                           const float* __restrict__ b1,
                                           const float* __restrict__ b2,
                                           float* __restrict__ out) {
    int idx = blockIdx.x * 256 + threadIdx.x;  // 0..65535
    int b = idx >> 10;
    int h = idx & 1023;
    float s = (h < HH) ? b1[h] : b2[h - HH];
#pragma unroll
    for (int ks = 0; ks < KSPLIT; ++ks) s += part[(size_t)ks * (BB * 1024) + idx];
    int which = h >> 9;
    out[S_ELEMS + (size_t)which * (BB * HH) + (size_t)b * HH + (h & 511)] = s;
}

extern "C" void kernel_launch(void* const* d_in, const int* in_sizes, int n_in,
                              void* d_out, int out_size, void* d_ws, size_t ws_size,
                              hipStream_t stream) {
    const float* feats = (const float*)d_in[0];
    const float* masks = (const float*)d_in[1];
    const float* W1 = (const float*)d_in[2];
    const float* b1 = (const float*)d_in[3];
    const float* W2 = (const float*)d_in[4];
    const float* b2 = (const float*)d_in[5];
    float* out = (float*)d_out;
    float* ws = (float*)d_ws;
    float* F = ws + WS_F;
    float* M = ws + WS_M;
    float* Sm = ws + WS_SM;
    float* part = ws + WS_PART;

    kA2<<<dim3(8, 64), 256, 0, stream>>>(feats, masks, F, M, Sm);
    kE<<<384, 256, 0, stream>>>(F, M, Sm, W1, W2, out, part);
    kD2<<<256, 256, 0, stream>>>(part, b1, b2, out);
}